// Round 5
// baseline (305.577 us; speedup 1.0000x reference)
//
#include <hip/hip_runtime.h>
#include <math.h>

#define NN 50000
#define EE 640000
#define IND 23
#define HID 128
#define MIDD 64
#define NCLS 12
#define NB 49          // ceil(NN / 1024) scan chunks
#define QS 32766.0f
#define INVQS (1.0f / 32766.0f)

typedef short short8v __attribute__((ext_vector_type(8)));
typedef float f32x4 __attribute__((ext_vector_type(4)));

// bf16 helpers (RNE), bit-exact and header-free
__device__ __forceinline__ short f2bf(float f) {
    unsigned u = __float_as_uint(f);
    unsigned r = (u + 0x7FFFu + ((u >> 16) & 1u)) >> 16;
    return (short)r;
}
__device__ __forceinline__ float bf2f(short s) {
    return __uint_as_float(((unsigned)(unsigned short)s) << 16);
}

// ---- fused pre-pass: edge count + head-collapse + weight split -------------
// blocks [0,2500): count   [2500,2506): Wcc=Wc1@Wc2   [2506,2634): W2/W3 split
__global__ __launch_bounds__(256) void k_pre(const int* __restrict__ dst,
                                             int* __restrict__ cnt,
                                             const float* __restrict__ Wc1,
                                             const float* __restrict__ bc1,
                                             const float* __restrict__ Wc2,
                                             const float* __restrict__ bc2,
                                             float* __restrict__ Wcc,
                                             float* __restrict__ bcc,
                                             const float* __restrict__ W2,
                                             const float* __restrict__ W3,
                                             short* __restrict__ w2hi,
                                             short* __restrict__ w2lo,
                                             short* __restrict__ w3hi,
                                             short* __restrict__ w3lo) {
    const int bid = blockIdx.x;
    const int tid = threadIdx.x;
    if (bid < 2500) {                       // edge count
        int i = bid * 256 + tid;
        if (i < EE) atomicAdd(&cnt[dst[i]], 1);
        return;
    }
    if (bid < 2506) {                       // collapsed head: Wcc, bcc
        int t = (bid - 2500) * 256 + tid;
        if (t < HID * NCLS) {
            int k = t / NCLS, c = t % NCLS;
            float s = 0.f;
#pragma unroll 8
            for (int j = 0; j < MIDD; ++j) s += Wc1[k * MIDD + j] * Wc2[j * NCLS + c];
            Wcc[t] = s;
        }
        if (t < NCLS) {
            float s = bc2[t];
#pragma unroll 8
            for (int j = 0; j < MIDD; ++j) s += bc1[j] * Wc2[j * NCLS + t];
            bcc[t] = s;
        }
        return;
    }
    // split W (128x128 fp32, k-major) into hi/lo bf16 MFMA B-fragment tables.
    // idx = ((t*4+g)*128 + col)*8 + j  <=>  W[t*32+g*8+j][col]
    int bb = bid - 2506;                    // 0..127
    const float* W = (bb < 64) ? W2 : W3;
    short* hi = (bb < 64) ? w2hi : w3hi;
    short* lo = (bb < 64) ? w2lo : w3lo;
    int i = (bb & 63) * 256 + tid;          // 0..16383
    int k = i >> 7, c = i & 127;
    float w = W[i];
    short h = f2bf(w);
    short l = f2bf(w - bf2f(h));
    int t = k >> 5, g = (k >> 3) & 3, j = k & 7;
    hi[((t * 4 + g) * 128 + c) * 8 + j] = h;
    lo[((t * 4 + g) * 128 + c) * 8 + j] = l;
}

__global__ __launch_bounds__(256) void k_scan_local(const int* __restrict__ cnt,
                                                    int* __restrict__ row_ptr,
                                                    float* __restrict__ dinv,
                                                    int* __restrict__ sums) {
    __shared__ int wtot[4];
    const int tid = threadIdx.x;
    const int wid = tid >> 6, lane = tid & 63;
    const int base = blockIdx.x * 1024 + tid * 4;
    int v[4];
#pragma unroll
    for (int t = 0; t < 4; ++t) {
        int i = base + t;
        v[t] = (i < NN) ? cnt[i] : 0;
        if (i < NN) dinv[i] = rsqrtf((float)v[t] + 1.0f);  // +1 self loop
    }
    int slocal = v[0] + v[1] + v[2] + v[3];
    int val = slocal;
#pragma unroll
    for (int off = 1; off < 64; off <<= 1) {
        int t = __shfl_up(val, off, 64);
        if (lane >= off) val += t;
    }
    if (lane == 63) wtot[wid] = val;
    __syncthreads();
    int woff = 0;
#pragma unroll
    for (int w = 0; w < 4; ++w) woff += (w < wid) ? wtot[w] : 0;
    int run = woff + val - slocal;
#pragma unroll
    for (int t = 0; t < 4; ++t) {
        int i = base + t;
        if (i < NN) row_ptr[i] = run;
        run += v[t];
    }
    if (tid == 255) sums[blockIdx.x] = woff + val;
}

// scan finalize; each block redundantly reduces the 49 partial sums (cheap),
// deleting the separate k_scan_sums launch
__global__ __launch_bounds__(256) void k_scan_apply2(int* __restrict__ row_ptr,
                                                     const int* __restrict__ sums,
                                                     int* __restrict__ cursor) {
    __shared__ int so;
    const int tid = threadIdx.x;
    if (tid < 64) {
        int a = (tid < (int)blockIdx.x) ? sums[tid] : 0;   // exclusive prefix
        int b = (tid < NB) ? sums[tid] : 0;                // grand total
#pragma unroll
        for (int off = 32; off; off >>= 1) {
            a += __shfl_down(a, off, 64);
            b += __shfl_down(b, off, 64);
        }
        if (tid == 0) {
            so = a;
            if (blockIdx.x == NB - 1) row_ptr[NN] = b;
        }
    }
    __syncthreads();
    const int o = so;
    const int base = blockIdx.x * 1024 + tid * 4;
#pragma unroll
    for (int t = 0; t < 4; ++t) {
        int i = base + t;
        if (i < NN) {
            int rp = row_ptr[i] + o;
            row_ptr[i] = rp;
            cursor[i] = rp;
        }
    }
}

// ---- fused fill + pad ------------------------------------------------------
// blocks [0,2500): CSR fill {src, dinv[src]}   [2500,8750): pad x -> xp
// The scatter store is NON-TEMPORAL: e_sn lines are written by blocks on all
// 8 XCDs; write-allocate in 8 non-coherent L2s caused ~8x HBM write
// amplification (R4: WRITE_SIZE 49 MB for 11.5 MB payload). nt bypasses L2.
__global__ __launch_bounds__(256) void k_fillpad(const int* __restrict__ src,
                                                 const int* __restrict__ dst,
                                                 int* __restrict__ cursor,
                                                 const float* __restrict__ dinv,
                                                 int2* __restrict__ e_sn,
                                                 const float* __restrict__ x,
                                                 float* __restrict__ xp) {
    const int bid = blockIdx.x;
    const int tid = threadIdx.x;
    if (bid < 2500) {
        int i = bid * 256 + tid;
        if (i < EE) {
            int s = src[i];
            int d = dst[i];
            float w = dinv[s];
            int pos = atomicAdd(&cursor[d], 1);
            unsigned long long pk = (unsigned)s |
                ((unsigned long long)__float_as_uint(w) << 32);
            __builtin_nontemporal_store(pk, (unsigned long long*)&e_sn[pos]);
        }
        return;
    }
    int i = (bid - 2500) * 256 + tid;       // over NN*32
    int node = i >> 5, f = i & 31;
    xp[i] = (f < IND) ? x[node * IND + f] * dinv[node] : 0.f;
}

// ---- layer 1 fused: q1 = quant( tanh( (A @ x) @ W1 + b1 ) ) ---------------
__global__ __launch_bounds__(256) void k_l1(const float* __restrict__ xp,
                                            const float* __restrict__ W1,
                                            const float* __restrict__ b1,
                                            const int* __restrict__ row_ptr,
                                            const int2* __restrict__ e_sn,
                                            const float* __restrict__ dinv,
                                            short* __restrict__ outq) {
    const int tid = threadIdx.x;
    const int i = blockIdx.x * 4 + (tid >> 6);
    const int lane = tid & 63;
    const int slot = lane >> 3;     // 8 edge slots
    const int f = lane & 7;         // float4 index within 32-float row
    const float4* xp4 = (const float4*)xp;
    const int beg = row_ptr[i];
    const int deg = row_ptr[i + 1] - beg;
    float4 acc = make_float4(0.f, 0.f, 0.f, 0.f);
    for (int base = 0; base < deg; base += 64) {
        const int cnt = min(64, deg - base);
        int s_l = 0;
        if (lane < cnt) s_l = e_sn[beg + base + lane].x;
        int e = 0;
        for (; e + 8 <= cnt; e += 8) {
            int s = __shfl(s_l, e + slot, 64);
            float4 v = xp4[s * 8 + f];
            acc.x += v.x; acc.y += v.y; acc.z += v.z; acc.w += v.w;
        }
        if (e < cnt) {                          // wave-uniform shfl
            int s = __shfl(s_l, e + slot, 64);
            if (e + slot < cnt) {
                float4 v = xp4[s * 8 + f];
                acc.x += v.x; acc.y += v.y; acc.z += v.z; acc.w += v.w;
            }
        }
    }
#pragma unroll
    for (int off = 32; off >= 8; off >>= 1) {
        acc.x += __shfl_down(acc.x, off, 64);
        acc.y += __shfl_down(acc.y, off, 64);
        acc.z += __shfl_down(acc.z, off, 64);
        acc.w += __shfl_down(acc.w, off, 64);
    }
    const float di = dinv[i];
    if (lane < 8) {
        float4 v = xp4[i * 8 + lane];   // self row (pre-folded)
        acc.x = (acc.x + v.x) * di; acc.y = (acc.y + v.y) * di;
        acc.z = (acc.z + v.z) * di; acc.w = (acc.w + v.w) * di;
    }
    float a0 = b1[lane], a1 = b1[lane + 64];
#pragma unroll
    for (int k = 0; k < IND; ++k) {
        float comp = ((k & 3) == 0) ? acc.x : ((k & 3) == 1) ? acc.y
                   : ((k & 3) == 2) ? acc.z : acc.w;
        float xk = __shfl(comp, k >> 2, 64);
        a0 += xk * W1[k * HID + lane];
        a1 += xk * W1[k * HID + lane + 64];
    }
    outq[i * HID + lane]      = (short)__float2int_rn(tanhf(a0) * QS);
    outq[i * HID + lane + 64] = (short)__float2int_rn(tanhf(a1) * QS);
}

// ---- aggregation over int16 tanh rows (lean, barrier-free, wave-per-node) --
// aggf_i = dinv_i * ( sum_s dinv_s*q_s + dinv_i*q_i ) / QS
// aggf store is NON-TEMPORAL: the 25.6 MB stream was evicting the 12.8 MB
// q working set the random gathers need resident in L2.
__global__ __launch_bounds__(256) void k_aggq(const short* __restrict__ hq,
                                              const int* __restrict__ row_ptr,
                                              const int2* __restrict__ e_sn,
                                              const float* __restrict__ dinv,
                                              float* __restrict__ aggf) {
    const int tid = threadIdx.x;
    const int i = blockIdx.x * 4 + (tid >> 6);
    const int lane = tid & 63;
    const int slot = lane >> 4;     // 4 edge slots
    const int f = lane & 15;        // short8 index within 128-short row
    const short8v* h8 = (const short8v*)hq;
    const int beg = row_ptr[i];
    const int deg = row_ptr[i + 1] - beg;
    float facc[8];
#pragma unroll
    for (int t = 0; t < 8; ++t) facc[t] = 0.f;
    for (int base = 0; base < deg; base += 64) {
        const int cnt = min(64, deg - base);
        int s_l = 0; float n_l = 0.f;
        if (lane < cnt) {
            int2 sn = e_sn[beg + base + lane];
            s_l = sn.x;
            n_l = __int_as_float(sn.y);
        }
        int e = 0;
#pragma unroll 4
        for (; e + 4 <= cnt; e += 4) {
            int s = __shfl(s_l, e + slot, 64);
            float nr = __shfl(n_l, e + slot, 64);
            short8v v = h8[s * 16 + f];
#pragma unroll
            for (int t = 0; t < 8; ++t) facc[t] += (float)v[t] * nr;
        }
        if (e < cnt) {                          // wave-uniform shfl
            int s = __shfl(s_l, e + slot, 64);
            float nr = __shfl(n_l, e + slot, 64);
            if (e + slot < cnt) {
                short8v v = h8[s * 16 + f];
#pragma unroll
                for (int t = 0; t < 8; ++t) facc[t] += (float)v[t] * nr;
            }
        }
    }
#pragma unroll
    for (int off = 32; off >= 16; off >>= 1)
#pragma unroll
        for (int t = 0; t < 8; ++t) facc[t] += __shfl_down(facc[t], off, 64);
    if (lane < 16) {
        const float di = dinv[i];
        const float sc = di * INVQS;
        short8v v = h8[i * 16 + lane];          // self row
        f32x4 o0, o1;
        o0[0] = (facc[0] + di * (float)v[0]) * sc;
        o0[1] = (facc[1] + di * (float)v[1]) * sc;
        o0[2] = (facc[2] + di * (float)v[2]) * sc;
        o0[3] = (facc[3] + di * (float)v[3]) * sc;
        o1[0] = (facc[4] + di * (float)v[4]) * sc;
        o1[1] = (facc[5] + di * (float)v[5]) * sc;
        o1[2] = (facc[6] + di * (float)v[6]) * sc;
        o1[3] = (facc[7] + di * (float)v[7]) * sc;
        f32x4* ag4 = (f32x4*)aggf;
        __builtin_nontemporal_store(o0, &ag4[i * 32 + lane * 2]);
        __builtin_nontemporal_store(o1, &ag4[i * 32 + lane * 2 + 1]);
    }
}

// ---- MFMA split-bf16 GEMM: C = A @ W via Ahi@Whi + Ahi@Wlo + Alo@Whi ------
// Wave = 16 rows x 128 cols; block = 64 rows. 96 mfma_f32_16x16x32_bf16/wave.
//   A: lane l holds A[l&15][8*(l>>4)+j]   B: lane l holds B[8*(l>>4)+j][l&15]
//   D: lane l holds D[4*(l>>4)+r][l&15]
// aggf rows are read exactly once -> nontemporal loads (don't evict q/W).
__device__ __forceinline__ void gemm_core(const float* __restrict__ hin,
                                          const short8v* __restrict__ whi8,
                                          const short8v* __restrict__ wlo8,
                                          int row, bool rv, int g, int c16,
                                          f32x4 acc[8]) {
#pragma unroll
    for (int t = 0; t < 4; ++t) {
        f32x4 a0 = {0.f, 0.f, 0.f, 0.f}, a1 = {0.f, 0.f, 0.f, 0.f};
        if (rv) {
            const f32x4* hp = (const f32x4*)&hin[row * HID + t * 32 + g * 8];
            a0 = __builtin_nontemporal_load(hp);
            a1 = __builtin_nontemporal_load(hp + 1);
        }
        short8v ahi, alo;
#pragma unroll
        for (int j = 0; j < 8; ++j) {
            float av = (j < 4) ? a0[j] : a1[j - 4];
            short h = f2bf(av);
            ahi[j] = h;
            alo[j] = f2bf(av - bf2f(h));
        }
        const int wb = (t * 4 + g) * 128 + c16;
#pragma unroll
        for (int n = 0; n < 8; ++n) {
            short8v bh = whi8[wb + n * 16];
            short8v bl = wlo8[wb + n * 16];
            acc[n] = __builtin_amdgcn_mfma_f32_16x16x32_bf16(ahi, bh, acc[n], 0, 0, 0);
            acc[n] = __builtin_amdgcn_mfma_f32_16x16x32_bf16(ahi, bl, acc[n], 0, 0, 0);
            acc[n] = __builtin_amdgcn_mfma_f32_16x16x32_bf16(alo, bh, acc[n], 0, 0, 0);
        }
    }
}

// layer 2: qout = int16 quant(tanh(A@W + b))
__global__ __launch_bounds__(256) void k_gemm_q(const float* __restrict__ hin,
                                                const short* __restrict__ whi,
                                                const short* __restrict__ wlo,
                                                const float* __restrict__ bias,
                                                short* __restrict__ qout) {
    const int tid = threadIdx.x;
    const int lane = tid & 63, w = tid >> 6;
    const int g = lane >> 4, c16 = lane & 15;
    const int rbase = blockIdx.x * 64 + w * 16;
    f32x4 acc[8];
#pragma unroll
    for (int n = 0; n < 8; ++n) acc[n] = f32x4{0.f, 0.f, 0.f, 0.f};
    gemm_core(hin, (const short8v*)whi, (const short8v*)wlo,
              rbase + c16, (rbase + c16) < NN, g, c16, acc);
#pragma unroll
    for (int n = 0; n < 8; ++n) {
        const float bb = bias[n * 16 + c16];
#pragma unroll
        for (int r = 0; r < 4; ++r) {
            int nd = rbase + 4 * g + r;
            if (nd < NN) {
                float v = tanhf(acc[n][r] + bb);
                qout[nd * HID + n * 16 + c16] = (short)__float2int_rn(v * QS);
            }
        }
    }
}

// layer 3 + fused head: out = tanh(A@W + b) @ Wcc + bcc  (h3 never hits HBM;
// head works directly on the MFMA D-register layout, 16-lane shfl reduce)
__global__ __launch_bounds__(256) void k_gemm_head(const float* __restrict__ hin,
                                                   const short* __restrict__ whi,
                                                   const short* __restrict__ wlo,
                                                   const float* __restrict__ bias,
                                                   const float* __restrict__ Wcc,
                                                   const float* __restrict__ bcc,
                                                   float* __restrict__ outp) {
    __shared__ float WccS[HID * NCLS + 16];
    const int tid = threadIdx.x;
    const int lane = tid & 63, w = tid >> 6;
    const int g = lane >> 4, c16 = lane & 15;
    const int rbase = blockIdx.x * 64 + w * 16;
    for (int t = tid; t < HID * NCLS; t += 256) WccS[t] = Wcc[t];
    if (tid < NCLS) WccS[HID * NCLS + tid] = bcc[tid];
    __syncthreads();
    f32x4 acc[8];
#pragma unroll
    for (int n = 0; n < 8; ++n) acc[n] = f32x4{0.f, 0.f, 0.f, 0.f};
    gemm_core(hin, (const short8v*)whi, (const short8v*)wlo,
              rbase + c16, (rbase + c16) < NN, g, c16, acc);
    float part[4][12];
#pragma unroll
    for (int r = 0; r < 4; ++r)
#pragma unroll
        for (int c = 0; c < 12; ++c) part[r][c] = 0.f;
#pragma unroll
    for (int n = 0; n < 8; ++n) {
        const float bb = bias[n * 16 + c16];
        const float4* wr = (const float4*)&WccS[(n * 16 + c16) * NCLS];
        float4 wa = wr[0], wb = wr[1], wc = wr[2];
#pragma unroll
        for (int r = 0; r < 4; ++r) {
            float v = tanhf(acc[n][r] + bb);
            part[r][0]  += v * wa.x; part[r][1]  += v * wa.y;
            part[r][2]  += v * wa.z; part[r][3]  += v * wa.w;
            part[r][4]  += v * wb.x; part[r][5]  += v * wb.y;
            part[r][6]  += v * wb.z; part[r][7]  += v * wb.w;
            part[r][8]  += v * wc.x; part[r][9]  += v * wc.y;
            part[r][10] += v * wc.z; part[r][11] += v * wc.w;
        }
    }
#pragma unroll
    for (int off = 8; off; off >>= 1)
#pragma unroll
        for (int r = 0; r < 4; ++r)
#pragma unroll
            for (int c = 0; c < 12; ++c)
                part[r][c] += __shfl_down(part[r][c], off, 64);
    if (c16 == 0) {
#pragma unroll
        for (int r = 0; r < 4; ++r) {
            int nd = rbase + 4 * g + r;
            if (nd < NN) {
                float4* op = (float4*)&outp[nd * NCLS];
                op[0] = make_float4(part[r][0] + WccS[HID * NCLS + 0],
                                    part[r][1] + WccS[HID * NCLS + 1],
                                    part[r][2] + WccS[HID * NCLS + 2],
                                    part[r][3] + WccS[HID * NCLS + 3]);
                op[1] = make_float4(part[r][4] + WccS[HID * NCLS + 4],
                                    part[r][5] + WccS[HID * NCLS + 5],
                                    part[r][6] + WccS[HID * NCLS + 6],
                                    part[r][7] + WccS[HID * NCLS + 7]);
                op[2] = make_float4(part[r][8] + WccS[HID * NCLS + 8],
                                    part[r][9] + WccS[HID * NCLS + 9],
                                    part[r][10] + WccS[HID * NCLS + 10],
                                    part[r][11] + WccS[HID * NCLS + 11]);
            }
        }
    }
}

// ---- launch ---------------------------------------------------------------

extern "C" void kernel_launch(void* const* d_in, const int* in_sizes, int n_in,
                              void* d_out, int out_size, void* d_ws, size_t ws_size,
                              hipStream_t stream) {
    const float* x    = (const float*)d_in[0];
    const int*   edge = (const int*)d_in[1];
    const int*   src  = edge;
    const int*   dst  = edge + EE;
    const float* W1  = (const float*)d_in[2];  const float* b1  = (const float*)d_in[3];
    const float* W2  = (const float*)d_in[4];  const float* b2  = (const float*)d_in[5];
    const float* W3  = (const float*)d_in[6];  const float* b3  = (const float*)d_in[7];
    const float* Wc1 = (const float*)d_in[8];  const float* bc1 = (const float*)d_in[9];
    const float* Wc2 = (const float*)d_in[10]; const float* bc2 = (const float*)d_in[11];
    float* outp = (float*)d_out;

    char* p = (char*)d_ws;
    int*   cnt     = (int*)p;   p += 200064;          // NN ints, padded
    int*   row_ptr = (int*)p;   p += 200064;          // NN+1 ints, padded
    float* dinv    = (float*)p; p += 200064;
    int*   sums    = (int*)p;   p += 256;
    int2*  e_sn    = (int2*)p;  p += (size_t)EE * 8;  // packed {src, dinv[src]}
    float* xp      = (float*)p; p += (size_t)NN * 32 * 4;    // padded pre-folded x
    short* q       = (short*)p; p += (size_t)NN * HID * 2;   // int16 tanh (q1/q2 alias)
    float* aggf    = (float*)p; p += (size_t)NN * HID * 4;   // fp32 agg (gemm input)
    float* Wcc     = (float*)p; p += HID * NCLS * 4;         // collapsed head weight
    float* bcc     = (float*)p; p += 256;                    // collapsed head bias
    short* w2hi    = (short*)p; p += 32768;           // bf16 frag tables (128x128)
    short* w2lo    = (short*)p; p += 32768;
    short* w3hi    = (short*)p; p += 32768;
    short* w3lo    = (short*)p; p += 32768;

    // graph build + weight preprocessing (fused front-end, 5 dispatches)
    hipMemsetAsync(cnt, 0, (size_t)NN * 4, stream);
    k_pre        <<<2634, 256, 0, stream>>>(dst, cnt, Wc1, bc1, Wc2, bc2, Wcc, bcc,
                                            W2, W3, w2hi, w2lo, w3hi, w3lo);
    k_scan_local <<<NB, 256, 0, stream>>>(cnt, row_ptr, dinv, sums);
    k_scan_apply2<<<NB, 256, 0, stream>>>(row_ptr, sums, cnt);   // cnt becomes cursor
    k_fillpad    <<<8750, 256, 0, stream>>>(src, dst, cnt, dinv, e_sn, x, xp);

    // layer 1: q1 = quant(tanh((A@x)@W1 + b1))
    k_l1  <<<NN / 4, 256, 0, stream>>>(xp, W1, b1, row_ptr, e_sn, dinv, q);
    // layer 2: agg(q1) -> mfma gemm+tanh -> q2   (q2 aliases q1; stream-ordered)
    k_aggq     <<<NN / 4, 256, 0, stream>>>(q, row_ptr, e_sn, dinv, aggf);
    k_gemm_q   <<<(NN + 63) / 64, 256, 0, stream>>>(aggf, w2hi, w2lo, b2, q);
    // layer 3: agg(q2) -> mfma gemm+tanh -> fused head (h3 never hits global)
    k_aggq     <<<NN / 4, 256, 0, stream>>>(q, row_ptr, e_sn, dinv, aggf);
    k_gemm_head<<<(NN + 63) / 64, 256, 0, stream>>>(aggf, w3hi, w3lo, b3, Wcc, bcc, outp);
}

// Round 7
// 284.845 us; speedup vs baseline: 1.0728x; 1.0728x over previous
//
#include <hip/hip_runtime.h>
#include <math.h>

#define NN 50000
#define EE 640000
#define IND 23
#define HID 128
#define MIDD 64
#define NCLS 12
#define NB 49          // ceil(NN / 1024) scan chunks
#define QS 32766.0f
#define INVQS (1.0f / 32766.0f)
#define BSH 7                       // bucket = dst >> 7  (128 nodes/bucket)
#define NBK 391                     // ceil(NN / 128)
#define CHUNK 4096                  // edges per partition block
#define NPB 157                     // ceil(EE / CHUNK)
#define PADB 6250                   // (NN*32)/256 pad blocks

typedef short short8v __attribute__((ext_vector_type(8)));
typedef float f32x4 __attribute__((ext_vector_type(4)));
typedef unsigned long long u64;

// bf16 helpers (RNE), bit-exact and header-free
__device__ __forceinline__ short f2bf(float f) {
    unsigned u = __float_as_uint(f);
    unsigned r = (u + 0x7FFFu + ((u >> 16) & 1u)) >> 16;
    return (short)r;
}
__device__ __forceinline__ float bf2f(short s) {
    return __uint_as_float(((unsigned)(unsigned short)s) << 16);
}

// ---- fused pre-pass: edge count + head-collapse + weight split -------------
// blocks [0,2500): count   [2500,2506): Wcc=Wc1@Wc2   [2506,2634): W2/W3 split
__global__ __launch_bounds__(256) void k_pre(const int* __restrict__ dst,
                                             int* __restrict__ cnt,
                                             const float* __restrict__ Wc1,
                                             const float* __restrict__ bc1,
                                             const float* __restrict__ Wc2,
                                             const float* __restrict__ bc2,
                                             float* __restrict__ Wcc,
                                             float* __restrict__ bcc,
                                             const float* __restrict__ W2,
                                             const float* __restrict__ W3,
                                             short* __restrict__ w2hi,
                                             short* __restrict__ w2lo,
                                             short* __restrict__ w3hi,
                                             short* __restrict__ w3lo) {
    const int bid = blockIdx.x;
    const int tid = threadIdx.x;
    if (bid < 2500) {                       // edge count
        int i = bid * 256 + tid;
        if (i < EE) atomicAdd(&cnt[dst[i]], 1);
        return;
    }
    if (bid < 2506) {                       // collapsed head: Wcc, bcc
        int t = (bid - 2500) * 256 + tid;
        if (t < HID * NCLS) {
            int k = t / NCLS, c = t % NCLS;
            float s = 0.f;
#pragma unroll 8
            for (int j = 0; j < MIDD; ++j) s += Wc1[k * MIDD + j] * Wc2[j * NCLS + c];
            Wcc[t] = s;
        }
        if (t < NCLS) {
            float s = bc2[t];
#pragma unroll 8
            for (int j = 0; j < MIDD; ++j) s += bc1[j] * Wc2[j * NCLS + t];
            bcc[t] = s;
        }
        return;
    }
    // split W (128x128 fp32, k-major) into hi/lo bf16 MFMA B-fragment tables.
    // idx = ((t*4+g)*128 + col)*8 + j  <=>  W[t*32+g*8+j][col]
    int bb = bid - 2506;                    // 0..127
    const float* W = (bb < 64) ? W2 : W3;
    short* hi = (bb < 64) ? w2hi : w3hi;
    short* lo = (bb < 64) ? w2lo : w3lo;
    int i = (bb & 63) * 256 + tid;          // 0..16383
    int k = i >> 7, c = i & 127;
    float w = W[i];
    short h = f2bf(w);
    short l = f2bf(w - bf2f(h));
    int t = k >> 5, g = (k >> 3) & 3, j = k & 7;
    hi[((t * 4 + g) * 128 + c) * 8 + j] = h;
    lo[((t * 4 + g) * 128 + c) * 8 + j] = l;
}

__global__ __launch_bounds__(256) void k_scan_local(const int* __restrict__ cnt,
                                                    int* __restrict__ row_ptr,
                                                    float* __restrict__ dinv,
                                                    int* __restrict__ sums) {
    __shared__ int wtot[4];
    const int tid = threadIdx.x;
    const int wid = tid >> 6, lane = tid & 63;
    const int base = blockIdx.x * 1024 + tid * 4;
    int v[4];
#pragma unroll
    for (int t = 0; t < 4; ++t) {
        int i = base + t;
        v[t] = (i < NN) ? cnt[i] : 0;
        if (i < NN) dinv[i] = rsqrtf((float)v[t] + 1.0f);  // +1 self loop
    }
    int slocal = v[0] + v[1] + v[2] + v[3];
    int val = slocal;
#pragma unroll
    for (int off = 1; off < 64; off <<= 1) {
        int t = __shfl_up(val, off, 64);
        if (lane >= off) val += t;
    }
    if (lane == 63) wtot[wid] = val;
    __syncthreads();
    int woff = 0;
#pragma unroll
    for (int w = 0; w < 4; ++w) woff += (w < wid) ? wtot[w] : 0;
    int run = woff + val - slocal;
#pragma unroll
    for (int t = 0; t < 4; ++t) {
        int i = base + t;
        if (i < NN) row_ptr[i] = run;
        run += v[t];
    }
    if (tid == 255) sums[blockIdx.x] = woff + val;
}

// scan finalize; each block redundantly reduces the 49 partial sums (cheap).
// Also initializes the per-bucket staging cursors bcurA[b] = row_ptr[b*128]
// (staging index space == final CSR index space).
__global__ __launch_bounds__(256) void k_scan_apply2(int* __restrict__ row_ptr,
                                                     const int* __restrict__ sums,
                                                     int* __restrict__ bcurA) {
    __shared__ int so;
    const int tid = threadIdx.x;
    if (tid < 64) {
        int a = (tid < (int)blockIdx.x) ? sums[tid] : 0;   // exclusive prefix
        int b = (tid < NB) ? sums[tid] : 0;                // grand total
#pragma unroll
        for (int off = 32; off; off >>= 1) {
            a += __shfl_down(a, off, 64);
            b += __shfl_down(b, off, 64);
        }
        if (tid == 0) {
            so = a;
            if (blockIdx.x == NB - 1) row_ptr[NN] = b;
        }
    }
    __syncthreads();
    const int o = so;
    const int base = blockIdx.x * 1024 + tid * 4;
#pragma unroll
    for (int t = 0; t < 4; ++t) {
        int i = base + t;
        if (i < NN) {
            int rp = row_ptr[i] + o;
            row_ptr[i] = rp;
            if ((i & 127) == 0) bcurA[i >> BSH] = rp;
        }
    }
}

// ---- pass A: bucket-partition edges (coalesced staged writes) + pad x -----
// blocks [0,NPB): partition CHUNK edges each via block-local counting sort
// by bucket dst>>7; staged {src,dinv[src]} + dst written in coalesced runs.
// Replaces the random 8B scatter whose 64B-line granularity cost 41 MB of
// HBM writes (R4/R5 measured; nt did not help).  blocks [NPB,NPB+PADB): pad.
// LDS = 6.2K (hist arrays) + 32K (lsw) + 16K (ld) = 55.4 KB. All barriers
// block-uniform; staged positions cover [row_ptr bucket region) exactly once.
__global__ __launch_bounds__(256) void k_part(const int* __restrict__ src,
                                              const int* __restrict__ dst,
                                              const float* __restrict__ dinv,
                                              int* __restrict__ bcurA,
                                              u64* __restrict__ sw_g,
                                              int* __restrict__ d_g,
                                              const float* __restrict__ x,
                                              float* __restrict__ xp) {
    const int bid = blockIdx.x;
    const int tid = threadIdx.x;
    if (bid >= NPB) {                       // pad x rows 23 -> 32, pre-folded
        int i = (bid - NPB) * 256 + tid;    // over NN*32
        int node = i >> 5, f = i & 31;
        xp[i] = (f < IND) ? x[node * IND + f] * dinv[node] : 0.f;
        return;
    }
    __shared__ int hist[NBK], base[NBK], cur[NBK], gb[NBK];
    __shared__ u64 lsw[CHUNK];
    __shared__ int ld[CHUNK];
    const int e0 = bid * CHUNK;
    const int total = min(CHUNK, EE - e0);
    for (int t = tid; t < NBK; t += 256) hist[t] = 0;
    __syncthreads();
    int sv[16], dv[16];
#pragma unroll
    for (int t = 0; t < 16; ++t) {
        int i = e0 + t * 256 + tid;
        if (i < EE) {
            sv[t] = src[i];
            dv[t] = dst[i];
            atomicAdd(&hist[dv[t] >> BSH], 1);
        } else dv[t] = -1;
    }
    __syncthreads();
    if (tid < 64) {                         // exclusive scan of hist (wave 0)
        int carry = 0;
        for (int c = 0; c < NBK; c += 64) {
            int idx = c + tid;
            int v = (idx < NBK) ? hist[idx] : 0;
            int sc = v;
#pragma unroll
            for (int off = 1; off < 64; off <<= 1) {
                int tv = __shfl_up(sc, off, 64);
                if (tid >= off) sc += tv;
            }
            if (idx < NBK) base[idx] = carry + sc - v;
            carry += __shfl(sc, 63, 64);
        }
    }
    __syncthreads();
    for (int t = tid; t < NBK; t += 256) {
        cur[t] = base[t];
        gb[t] = hist[t] ? atomicAdd(&bcurA[t], hist[t]) : 0;
    }
    __syncthreads();
#pragma unroll
    for (int t = 0; t < 16; ++t) {
        if (dv[t] >= 0) {
            int b = dv[t] >> BSH;
            int r = atomicAdd(&cur[b], 1);
            lsw[r] = (unsigned)sv[t] |
                     ((u64)__float_as_uint(dinv[sv[t]]) << 32);
            ld[r] = dv[t];
        }
    }
    __syncthreads();
    for (int j = tid; j < total; j += 256) {    // coalesced run flush
        int d = ld[j];
        int b = d >> BSH;
        int gpos = gb[b] + (j - base[b]);
        sw_g[gpos] = lsw[j];
        d_g[gpos] = d;
    }
}

// ---- pass B: exact per-bucket counting sort into CSR (coalesced I/O) ------
// One block per bucket (128 nodes). All of a bucket's edges are already in
// its contiguous staging region; sort to per-node position through LDS and
// write e_sn fully coalesced. Overflow fallback (pl >= 3072) writes positions
// disjoint from the flush loop (statistically never hit: mean 1638, sigma 40).
__global__ __launch_bounds__(256) void k_sort(const int* __restrict__ row_ptr,
                                              const u64* __restrict__ sw_g,
                                              const int* __restrict__ d_g,
                                              u64* __restrict__ e_sn) {
    __shared__ int rloc[129];
    __shared__ int curl[128];
    __shared__ u64 osw[3072];
    const int bid = blockIdx.x, tid = threadIdx.x;
    const int n0 = bid << BSH;
    const int nlast = min(128, NN - n0);
    if (tid <= nlast) rloc[tid] = row_ptr[n0 + tid];
    if (tid < 128) curl[tid] = 0;
    __syncthreads();
    const int rbeg = rloc[0];
    const int cnt = rloc[nlast] - rbeg;
    for (int j = tid; j < cnt; j += 256) {
        int d = d_g[rbeg + j];
        int li = d - n0;
        int r = atomicAdd(&curl[li], 1);
        int pl = (rloc[li] - rbeg) + r;
        u64 v = sw_g[rbeg + j];
        if (pl < 3072) osw[pl] = v;
        else e_sn[rbeg + pl] = v;           // overflow fallback (never hit)
    }
    __syncthreads();
    const int lim = min(cnt, 3072);
    for (int j = tid; j < lim; j += 256) e_sn[rbeg + j] = osw[j];
}

// ---- layer 1 fused: q1 = quant( tanh( (A @ x) @ W1 + b1 ) ) ---------------
__global__ __launch_bounds__(256) void k_l1(const float* __restrict__ xp,
                                            const float* __restrict__ W1,
                                            const float* __restrict__ b1,
                                            const int* __restrict__ row_ptr,
                                            const int2* __restrict__ e_sn,
                                            const float* __restrict__ dinv,
                                            short* __restrict__ outq) {
    const int tid = threadIdx.x;
    const int i = blockIdx.x * 4 + (tid >> 6);
    const int lane = tid & 63;
    const int slot = lane >> 3;     // 8 edge slots
    const int f = lane & 7;         // float4 index within 32-float row
    const float4* xp4 = (const float4*)xp;
    const int beg = row_ptr[i];
    const int deg = row_ptr[i + 1] - beg;
    float4 acc = make_float4(0.f, 0.f, 0.f, 0.f);
    for (int base = 0; base < deg; base += 64) {
        const int cnt = min(64, deg - base);
        int s_l = 0;
        if (lane < cnt) s_l = e_sn[beg + base + lane].x;
        int e = 0;
        for (; e + 8 <= cnt; e += 8) {
            int s = __shfl(s_l, e + slot, 64);
            float4 v = xp4[s * 8 + f];
            acc.x += v.x; acc.y += v.y; acc.z += v.z; acc.w += v.w;
        }
        if (e < cnt) {                          // wave-uniform shfl
            int s = __shfl(s_l, e + slot, 64);
            if (e + slot < cnt) {
                float4 v = xp4[s * 8 + f];
                acc.x += v.x; acc.y += v.y; acc.z += v.z; acc.w += v.w;
            }
        }
    }
#pragma unroll
    for (int off = 32; off >= 8; off >>= 1) {
        acc.x += __shfl_down(acc.x, off, 64);
        acc.y += __shfl_down(acc.y, off, 64);
        acc.z += __shfl_down(acc.z, off, 64);
        acc.w += __shfl_down(acc.w, off, 64);
    }
    const float di = dinv[i];
    if (lane < 8) {
        float4 v = xp4[i * 8 + lane];   // self row (pre-folded)
        acc.x = (acc.x + v.x) * di; acc.y = (acc.y + v.y) * di;
        acc.z = (acc.z + v.z) * di; acc.w = (acc.w + v.w) * di;
    }
    float a0 = b1[lane], a1 = b1[lane + 64];
#pragma unroll
    for (int k = 0; k < IND; ++k) {
        float comp = ((k & 3) == 0) ? acc.x : ((k & 3) == 1) ? acc.y
                   : ((k & 3) == 2) ? acc.z : acc.w;
        float xk = __shfl(comp, k >> 2, 64);
        a0 += xk * W1[k * HID + lane];
        a1 += xk * W1[k * HID + lane + 64];
    }
    outq[i * HID + lane]      = (short)__float2int_rn(tanhf(a0) * QS);
    outq[i * HID + lane + 64] = (short)__float2int_rn(tanhf(a1) * QS);
}

// ---- aggregation over int16 tanh rows (lean, barrier-free, wave-per-node) --
// aggf_i = dinv_i * ( sum_s dinv_s*q_s + dinv_i*q_i ) / QS
__global__ __launch_bounds__(256) void k_aggq(const short* __restrict__ hq,
                                              const int* __restrict__ row_ptr,
                                              const int2* __restrict__ e_sn,
                                              const float* __restrict__ dinv,
                                              float* __restrict__ aggf) {
    const int tid = threadIdx.x;
    const int i = blockIdx.x * 4 + (tid >> 6);
    const int lane = tid & 63;
    const int slot = lane >> 4;     // 4 edge slots
    const int f = lane & 15;        // short8 index within 128-short row
    const short8v* h8 = (const short8v*)hq;
    const int beg = row_ptr[i];
    const int deg = row_ptr[i + 1] - beg;
    float facc[8];
#pragma unroll
    for (int t = 0; t < 8; ++t) facc[t] = 0.f;
    for (int base = 0; base < deg; base += 64) {
        const int cnt = min(64, deg - base);
        int s_l = 0; float n_l = 0.f;
        if (lane < cnt) {
            int2 sn = e_sn[beg + base + lane];
            s_l = sn.x;
            n_l = __int_as_float(sn.y);
        }
        int e = 0;
#pragma unroll 4
        for (; e + 4 <= cnt; e += 4) {
            int s = __shfl(s_l, e + slot, 64);
            float nr = __shfl(n_l, e + slot, 64);
            short8v v = h8[s * 16 + f];
#pragma unroll
            for (int t = 0; t < 8; ++t) facc[t] += (float)v[t] * nr;
        }
        if (e < cnt) {                          // wave-uniform shfl
            int s = __shfl(s_l, e + slot, 64);
            float nr = __shfl(n_l, e + slot, 64);
            if (e + slot < cnt) {
                short8v v = h8[s * 16 + f];
#pragma unroll
                for (int t = 0; t < 8; ++t) facc[t] += (float)v[t] * nr;
            }
        }
    }
#pragma unroll
    for (int off = 32; off >= 16; off >>= 1)
#pragma unroll
        for (int t = 0; t < 8; ++t) facc[t] += __shfl_down(facc[t], off, 64);
    if (lane < 16) {
        const float di = dinv[i];
        const float sc = di * INVQS;
        short8v v = h8[i * 16 + lane];          // self row
        float4 o0, o1;
        o0.x = (facc[0] + di * (float)v[0]) * sc;
        o0.y = (facc[1] + di * (float)v[1]) * sc;
        o0.z = (facc[2] + di * (float)v[2]) * sc;
        o0.w = (facc[3] + di * (float)v[3]) * sc;
        o1.x = (facc[4] + di * (float)v[4]) * sc;
        o1.y = (facc[5] + di * (float)v[5]) * sc;
        o1.z = (facc[6] + di * (float)v[6]) * sc;
        o1.w = (facc[7] + di * (float)v[7]) * sc;
        ((float4*)aggf)[i * 32 + lane * 2]     = o0;
        ((float4*)aggf)[i * 32 + lane * 2 + 1] = o1;
    }
}

// ---- MFMA split-bf16 GEMM: C = A @ W via Ahi@Whi + Ahi@Wlo + Alo@Whi ------
// Wave = 16 rows x 128 cols; block = 64 rows. 96 mfma_f32_16x16x32_bf16/wave.
//   A: lane l holds A[l&15][8*(l>>4)+j]   B: lane l holds B[8*(l>>4)+j][l&15]
//   D: lane l holds D[4*(l>>4)+r][l&15]
__device__ __forceinline__ void gemm_core(const float* __restrict__ hin,
                                          const short8v* __restrict__ whi8,
                                          const short8v* __restrict__ wlo8,
                                          int row, bool rv, int g, int c16,
                                          f32x4 acc[8]) {
#pragma unroll
    for (int t = 0; t < 4; ++t) {
        float4 a0 = make_float4(0.f, 0.f, 0.f, 0.f), a1 = a0;
        if (rv) {
            const float4* hp = (const float4*)&hin[row * HID + t * 32 + g * 8];
            a0 = hp[0]; a1 = hp[1];
        }
        float av[8];
        av[0] = a0.x; av[1] = a0.y; av[2] = a0.z; av[3] = a0.w;
        av[4] = a1.x; av[5] = a1.y; av[6] = a1.z; av[7] = a1.w;
        short8v ahi, alo;
#pragma unroll
        for (int j = 0; j < 8; ++j) {
            short h = f2bf(av[j]);
            ahi[j] = h;
            alo[j] = f2bf(av[j] - bf2f(h));
        }
        const int wb = (t * 4 + g) * 128 + c16;
#pragma unroll
        for (int n = 0; n < 8; ++n) {
            short8v bh = whi8[wb + n * 16];
            short8v bl = wlo8[wb + n * 16];
            acc[n] = __builtin_amdgcn_mfma_f32_16x16x32_bf16(ahi, bh, acc[n], 0, 0, 0);
            acc[n] = __builtin_amdgcn_mfma_f32_16x16x32_bf16(ahi, bl, acc[n], 0, 0, 0);
            acc[n] = __builtin_amdgcn_mfma_f32_16x16x32_bf16(alo, bh, acc[n], 0, 0, 0);
        }
    }
}

// layer 2: qout = int16 quant(tanh(A@W + b))
__global__ __launch_bounds__(256) void k_gemm_q(const float* __restrict__ hin,
                                                const short* __restrict__ whi,
                                                const short* __restrict__ wlo,
                                                const float* __restrict__ bias,
                                                short* __restrict__ qout) {
    const int tid = threadIdx.x;
    const int lane = tid & 63, w = tid >> 6;
    const int g = lane >> 4, c16 = lane & 15;
    const int rbase = blockIdx.x * 64 + w * 16;
    f32x4 acc[8];
#pragma unroll
    for (int n = 0; n < 8; ++n) acc[n] = f32x4{0.f, 0.f, 0.f, 0.f};
    gemm_core(hin, (const short8v*)whi, (const short8v*)wlo,
              rbase + c16, (rbase + c16) < NN, g, c16, acc);
#pragma unroll
    for (int n = 0; n < 8; ++n) {
        const float bb = bias[n * 16 + c16];
#pragma unroll
        for (int r = 0; r < 4; ++r) {
            int nd = rbase + 4 * g + r;
            if (nd < NN) {
                float v = tanhf(acc[n][r] + bb);
                qout[nd * HID + n * 16 + c16] = (short)__float2int_rn(v * QS);
            }
        }
    }
}

// layer 3 + fused head: out = tanh(A@W + b) @ Wcc + bcc  (h3 never hits HBM;
// head works directly on the MFMA D-register layout, 16-lane shfl reduce)
__global__ __launch_bounds__(256) void k_gemm_head(const float* __restrict__ hin,
                                                   const short* __restrict__ whi,
                                                   const short* __restrict__ wlo,
                                                   const float* __restrict__ bias,
                                                   const float* __restrict__ Wcc,
                                                   const float* __restrict__ bcc,
                                                   float* __restrict__ outp) {
    __shared__ float WccS[HID * NCLS + 16];
    const int tid = threadIdx.x;
    const int lane = tid & 63, w = tid >> 6;
    const int g = lane >> 4, c16 = lane & 15;
    const int rbase = blockIdx.x * 64 + w * 16;
    for (int t = tid; t < HID * NCLS; t += 256) WccS[t] = Wcc[t];
    if (tid < NCLS) WccS[HID * NCLS + tid] = bcc[tid];
    __syncthreads();
    f32x4 acc[8];
#pragma unroll
    for (int n = 0; n < 8; ++n) acc[n] = f32x4{0.f, 0.f, 0.f, 0.f};
    gemm_core(hin, (const short8v*)whi, (const short8v*)wlo,
              rbase + c16, (rbase + c16) < NN, g, c16, acc);
    float part[4][12];
#pragma unroll
    for (int r = 0; r < 4; ++r)
#pragma unroll
        for (int c = 0; c < 12; ++c) part[r][c] = 0.f;
#pragma unroll
    for (int n = 0; n < 8; ++n) {
        const float bb = bias[n * 16 + c16];
        const float4* wr = (const float4*)&WccS[(n * 16 + c16) * NCLS];
        float4 wa = wr[0], wb = wr[1], wc = wr[2];
#pragma unroll
        for (int r = 0; r < 4; ++r) {
            float v = tanhf(acc[n][r] + bb);
            part[r][0]  += v * wa.x; part[r][1]  += v * wa.y;
            part[r][2]  += v * wa.z; part[r][3]  += v * wa.w;
            part[r][4]  += v * wb.x; part[r][5]  += v * wb.y;
            part[r][6]  += v * wb.z; part[r][7]  += v * wb.w;
            part[r][8]  += v * wc.x; part[r][9]  += v * wc.y;
            part[r][10] += v * wc.z; part[r][11] += v * wc.w;
        }
    }
#pragma unroll
    for (int off = 8; off; off >>= 1)
#pragma unroll
        for (int r = 0; r < 4; ++r)
#pragma unroll
            for (int c = 0; c < 12; ++c)
                part[r][c] += __shfl_down(part[r][c], off, 64);
    if (c16 == 0) {
#pragma unroll
        for (int r = 0; r < 4; ++r) {
            int nd = rbase + 4 * g + r;
            if (nd < NN) {
                float4* op = (float4*)&outp[nd * NCLS];
                op[0] = make_float4(part[r][0] + WccS[HID * NCLS + 0],
                                    part[r][1] + WccS[HID * NCLS + 1],
                                    part[r][2] + WccS[HID * NCLS + 2],
                                    part[r][3] + WccS[HID * NCLS + 3]);
                op[1] = make_float4(part[r][4] + WccS[HID * NCLS + 4],
                                    part[r][5] + WccS[HID * NCLS + 5],
                                    part[r][6] + WccS[HID * NCLS + 6],
                                    part[r][7] + WccS[HID * NCLS + 7]);
                op[2] = make_float4(part[r][8] + WccS[HID * NCLS + 8],
                                    part[r][9] + WccS[HID * NCLS + 9],
                                    part[r][10] + WccS[HID * NCLS + 10],
                                    part[r][11] + WccS[HID * NCLS + 11]);
            }
        }
    }
}

// ---- launch ---------------------------------------------------------------

extern "C" void kernel_launch(void* const* d_in, const int* in_sizes, int n_in,
                              void* d_out, int out_size, void* d_ws, size_t ws_size,
                              hipStream_t stream) {
    const float* x    = (const float*)d_in[0];
    const int*   edge = (const int*)d_in[1];
    const int*   src  = edge;
    const int*   dst  = edge + EE;
    const float* W1  = (const float*)d_in[2];  const float* b1  = (const float*)d_in[3];
    const float* W2  = (const float*)d_in[4];  const float* b2  = (const float*)d_in[5];
    const float* W3  = (const float*)d_in[6];  const float* b3  = (const float*)d_in[7];
    const float* Wc1 = (const float*)d_in[8];  const float* bc1 = (const float*)d_in[9];
    const float* Wc2 = (const float*)d_in[10]; const float* bc2 = (const float*)d_in[11];
    float* outp = (float*)d_out;

    char* p = (char*)d_ws;
    int*   cnt     = (int*)p;   p += 200064;          // NN ints, padded
    int*   row_ptr = (int*)p;   p += 200064;          // NN+1 ints, padded
    float* dinv    = (float*)p; p += 200064;
    int*   sums    = (int*)p;   p += 256;
    int*   bcurA   = (int*)p;   p += 2048;            // NBK staging cursors
    int2*  e_sn    = (int2*)p;  p += (size_t)EE * 8;  // sorted {src, dinv[src]}
    u64*   sw_g    = (u64*)p;   p += (size_t)EE * 8;  // staged {src, dinv}
    int*   d_g     = (int*)p;   p += (size_t)EE * 4;  // staged dst
    float* xp      = (float*)p; p += (size_t)NN * 32 * 4;    // padded pre-folded x
    short* q       = (short*)p; p += (size_t)NN * HID * 2;   // int16 tanh (q1/q2 alias)
    float* aggf    = (float*)p; p += (size_t)NN * HID * 4;   // fp32 agg (gemm input)
    float* Wcc     = (float*)p; p += HID * NCLS * 4;         // collapsed head weight
    float* bcc     = (float*)p; p += 256;                    // collapsed head bias
    short* w2hi    = (short*)p; p += 32768;           // bf16 frag tables (128x128)
    short* w2lo    = (short*)p; p += 32768;
    short* w3hi    = (short*)p; p += 32768;
    short* w3lo    = (short*)p; p += 32768;

    // graph build + weight preprocessing
    hipMemsetAsync(cnt, 0, (size_t)NN * 4, stream);
    k_pre        <<<2634, 256, 0, stream>>>(dst, cnt, Wc1, bc1, Wc2, bc2, Wcc, bcc,
                                            W2, W3, w2hi, w2lo, w3hi, w3lo);
    k_scan_local <<<NB, 256, 0, stream>>>(cnt, row_ptr, dinv, sums);
    k_scan_apply2<<<NB, 256, 0, stream>>>(row_ptr, sums, bcurA);
    k_part       <<<NPB + PADB, 256, 0, stream>>>(src, dst, dinv, bcurA,
                                                  sw_g, d_g, x, xp);
    k_sort       <<<NBK, 256, 0, stream>>>(row_ptr, sw_g, d_g, (u64*)e_sn);

    // layer 1: q1 = quant(tanh((A@x)@W1 + b1))
    k_l1  <<<NN / 4, 256, 0, stream>>>(xp, W1, b1, row_ptr, e_sn, dinv, q);
    // layer 2: agg(q1) -> mfma gemm+tanh -> q2   (q2 aliases q1; stream-ordered)
    k_aggq     <<<NN / 4, 256, 0, stream>>>(q, row_ptr, e_sn, dinv, aggf);
    k_gemm_q   <<<(NN + 63) / 64, 256, 0, stream>>>(aggf, w2hi, w2lo, b2, q);
    // layer 3: agg(q2) -> mfma gemm+tanh -> fused head (h3 never hits global)
    k_aggq     <<<NN / 4, 256, 0, stream>>>(q, row_ptr, e_sn, dinv, aggf);
    k_gemm_head<<<(NN + 63) / 64, 256, 0, stream>>>(aggf, w3hi, w3lo, b3, Wcc, bcc, outp);
}